// Round 1
// baseline (2265.599 us; speedup 1.0000x reference)
//
#include <hip/hip_runtime.h>
#include <hip/hip_bf16.h>
#include <math.h>

#define B_  8
#define T_  4096
#define D_  1024
#define H_  2048
#define E_  8
#define SP_ 64
#define S_  512
#define N_  (B_ * T_)   // 32768 rows

// ---------------- common 64x64 tile fp32 GEMM micro-kernel ----------------
// 256 threads, each computes a 4x4 micro-tile; BK=16; LDS As/Bs are [k][m]/[k][n].

#define FMA16(a, b) \
    acc[0][0] = fmaf(a.x, b.x, acc[0][0]); \
    acc[0][1] = fmaf(a.x, b.y, acc[0][1]); \
    acc[0][2] = fmaf(a.x, b.z, acc[0][2]); \
    acc[0][3] = fmaf(a.x, b.w, acc[0][3]); \
    acc[1][0] = fmaf(a.y, b.x, acc[1][0]); \
    acc[1][1] = fmaf(a.y, b.y, acc[1][1]); \
    acc[1][2] = fmaf(a.y, b.z, acc[1][2]); \
    acc[1][3] = fmaf(a.y, b.w, acc[1][3]); \
    acc[2][0] = fmaf(a.z, b.x, acc[2][0]); \
    acc[2][1] = fmaf(a.z, b.y, acc[2][1]); \
    acc[2][2] = fmaf(a.z, b.z, acc[2][2]); \
    acc[2][3] = fmaf(a.z, b.w, acc[2][3]); \
    acc[3][0] = fmaf(a.w, b.x, acc[3][0]); \
    acc[3][1] = fmaf(a.w, b.y, acc[3][1]); \
    acc[3][2] = fmaf(a.w, b.z, acc[3][2]); \
    acc[3][3] = fmaf(a.w, b.w, acc[3][3]);

#define COMPUTE_TILE() \
    _Pragma("unroll") \
    for (int kk = 0; kk < 16; ++kk) { \
        float4 a = *(const float4*)&As[kk][ty << 2]; \
        float4 b = *(const float4*)&Bs[kk][tx << 2]; \
        FMA16(a, b) \
    }

// ---------------- kernel 1: logits = x @ Wr^T + expert_bias ----------------
// A = x (N x D) row-major, B = Wr (S x D) row-major (so C = A * B^T), C = logits (N x S)
__global__ __launch_bounds__(256) void k_logits(const float* __restrict__ x,
                                                const float* __restrict__ Wr,
                                                const float* __restrict__ ebias,
                                                float* __restrict__ logits) {
    __shared__ float As[16][64];
    __shared__ float Bs[16][64];
    const int tid = threadIdx.x;
    const int tx = tid & 15, ty = tid >> 4;
    const int lr = tid >> 2;            // row within tile (0..63)
    const int lk = (tid & 3) << 2;      // k offset (0,4,8,12)
    const int s0 = blockIdx.x * 64;
    const int n0 = blockIdx.y * 64;
    const float bias = ebias[blockIdx.x];  // SP_ == 64 -> one expert per s-tile
    const float* Arow = x  + (size_t)(n0 + lr) * D_ + lk;
    const float* Brow = Wr + (size_t)(s0 + lr) * D_ + lk;
    float acc[4][4] = {};
    for (int k0 = 0; k0 < D_; k0 += 16) {
        float4 av = *(const float4*)(Arow + k0);
        float4 bv = *(const float4*)(Brow + k0);
        __syncthreads();
        As[lk + 0][lr] = av.x; As[lk + 1][lr] = av.y;
        As[lk + 2][lr] = av.z; As[lk + 3][lr] = av.w;
        Bs[lk + 0][lr] = bv.x; Bs[lk + 1][lr] = bv.y;
        Bs[lk + 2][lr] = bv.z; Bs[lk + 3][lr] = bv.w;
        __syncthreads();
        COMPUTE_TILE()
    }
#pragma unroll
    for (int i = 0; i < 4; ++i) {
        const int n = n0 + (ty << 2) + i;
        float4 o = make_float4(acc[i][0] + bias, acc[i][1] + bias,
                               acc[i][2] + bias, acc[i][3] + bias);
        *(float4*)(logits + (size_t)n * S_ + s0 + (tx << 2)) = o;
    }
}

// ---------------- kernel 2a: per-chunk column (token-axis) softmax stats ----------------
// grid (S/64, B, 8 chunks); online max/sum over t in chunk
__global__ __launch_bounds__(256) void k_colpart(const float* __restrict__ logits,
                                                 float* __restrict__ pm,
                                                 float* __restrict__ pl) {
    const int tid = threadIdx.x;
    const int sl = tid & 63;
    const int s = blockIdx.x * 64 + sl;
    const int b = blockIdx.y;
    const int c = blockIdx.z;
    const int tg = tid >> 6;              // 4 t-groups
    const int t0 = c * (T_ / 8);
    float m = -1e30f, l = 0.f;
    for (int t = t0 + tg; t < t0 + T_ / 8; t += 4) {
        float v = logits[((size_t)b * T_ + t) * S_ + s];
        if (v > m) { l = l * __expf(m - v) + 1.0f; m = v; }
        else       { l += __expf(v - m); }
    }
    __shared__ float sm[4][64], slds[4][64];
    sm[tg][sl] = m; slds[tg][sl] = l;
    __syncthreads();
    if (tg == 0) {
#pragma unroll
        for (int g = 1; g < 4; ++g) {
            float m2 = sm[g][sl], l2 = slds[g][sl];
            float mn = fmaxf(m, m2);
            l = l * __expf(m - mn) + l2 * __expf(m2 - mn);
            m = mn;
        }
        pm[(size_t)c * (B_ * S_) + b * S_ + s] = m;
        pl[(size_t)c * (B_ * S_) + b * S_ + s] = l;
    }
}

// ---------------- kernel 2b: combine 8 chunk partials -> colmax, colrcp ----------------
__global__ __launch_bounds__(256) void k_colcomb(const float* __restrict__ pm,
                                                 const float* __restrict__ pl,
                                                 float* __restrict__ colmax,
                                                 float* __restrict__ colrcp) {
    const int i = blockIdx.x * 256 + threadIdx.x;   // 0..B*S-1
    float m = -1e30f, l = 0.f;
#pragma unroll
    for (int c = 0; c < 8; ++c) {
        float m2 = pm[(size_t)c * (B_ * S_) + i];
        float l2 = pl[(size_t)c * (B_ * S_) + i];
        float mn = fmaxf(m, m2);
        l = l * __expf(m - mn) + l2 * __expf(m2 - mn);
        m = mn;
    }
    colmax[i] = m;
    colrcp[i] = 1.0f / l;
}

// ---------------- kernel 3: row (slot-axis) softmax stats ----------------
// one wave per row of 512; 4 waves per block
__global__ __launch_bounds__(256) void k_rowstats(const float* __restrict__ logits,
                                                  float* __restrict__ rowmax,
                                                  float* __restrict__ rowrcp) {
    const int tid = threadIdx.x;
    const int lane = tid & 63;
    const int n = blockIdx.x * 4 + (tid >> 6);
    const float* row = logits + (size_t)n * S_;
    float v[8];
    float m = -1e30f;
#pragma unroll
    for (int i = 0; i < 8; ++i) { v[i] = row[lane + i * 64]; m = fmaxf(m, v[i]); }
#pragma unroll
    for (int off = 32; off; off >>= 1) m = fmaxf(m, __shfl_xor(m, off, 64));
    float l = 0.f;
#pragma unroll
    for (int i = 0; i < 8; ++i) l += __expf(v[i] - m);
#pragma unroll
    for (int off = 32; off; off >>= 1) l += __shfl_xor(l, off, 64);
    if (lane == 0) { rowmax[n] = m; rowrcp[n] = 1.0f / l; }
}

// ---------------- kernel 4: slot_in[b,s,:] = sum_t dispatch[b,t,s] * x[b,t,:] ----------------
// A^T = logits (T x S) k-major with exp transform; B = x (T x D) k-major; K = T
__global__ __launch_bounds__(256) void k_slotin(const float* __restrict__ logits,
                                                const float* __restrict__ x,
                                                const float* __restrict__ colmax,
                                                const float* __restrict__ colrcp,
                                                float* __restrict__ slot_in) {
    __shared__ float As[16][64];
    __shared__ float Bs[16][64];
    const int tid = threadIdx.x;
    const int tx = tid & 15, ty = tid >> 4;
    const int lkk = tid >> 4;            // k row within tile (0..15)
    const int lm = (tid & 15) << 2;      // col offset (0..60)
    const int d0 = blockIdx.x * 64;
    const int s0 = blockIdx.y * 64;
    const int b  = blockIdx.z;
    const float4 cm = *(const float4*)(colmax + b * S_ + s0 + lm);
    const float4 cr = *(const float4*)(colrcp + b * S_ + s0 + lm);
    const float* Abase = logits + ((size_t)b * T_ + lkk) * S_ + s0 + lm;
    const float* Bbase = x      + ((size_t)b * T_ + lkk) * D_ + d0 + lm;
    float acc[4][4] = {};
    for (int k0 = 0; k0 < T_; k0 += 16) {
        float4 av = *(const float4*)(Abase + (size_t)k0 * S_);
        float4 bv = *(const float4*)(Bbase + (size_t)k0 * D_);
        av.x = __expf(av.x - cm.x) * cr.x;
        av.y = __expf(av.y - cm.y) * cr.y;
        av.z = __expf(av.z - cm.z) * cr.z;
        av.w = __expf(av.w - cm.w) * cr.w;
        __syncthreads();
        *(float4*)&As[lkk][lm] = av;
        *(float4*)&Bs[lkk][lm] = bv;
        __syncthreads();
        COMPUTE_TILE()
    }
#pragma unroll
    for (int i = 0; i < 4; ++i) {
        const int s = s0 + (ty << 2) + i;
        float4 o = make_float4(acc[i][0], acc[i][1], acc[i][2], acc[i][3]);
        *(float4*)(slot_in + ((size_t)b * S_ + s) * D_ + d0 + (tx << 2)) = o;
    }
}

// ---------------- kernel 5: h = gelu(slot_in @ W1[e] + b1[e]) ----------------
// grid (H/64, B, E); A rows are (b, e, sp=0..63); h layout (E, B*64, H)
__global__ __launch_bounds__(256) void k_ffn1(const float* __restrict__ slot_in,
                                              const float* __restrict__ W1,
                                              const float* __restrict__ b1,
                                              float* __restrict__ h) {
    __shared__ float As[16][64];
    __shared__ float Bs[16][64];
    const int tid = threadIdx.x;
    const int tx = tid & 15, ty = tid >> 4;
    const int lr = tid >> 2, lk = (tid & 3) << 2;
    const int lkk = tid >> 4, lm = (tid & 15) << 2;
    const int n0 = blockIdx.x * 64;
    const int b  = blockIdx.y;
    const int e  = blockIdx.z;
    const float* Arow  = slot_in + ((size_t)(b * S_ + e * SP_) + lr) * D_ + lk;
    const float* Bbase = W1 + (size_t)e * D_ * H_ + (size_t)lkk * H_ + n0 + lm;
    float acc[4][4] = {};
    for (int k0 = 0; k0 < D_; k0 += 16) {
        float4 av = *(const float4*)(Arow + k0);
        float4 bv = *(const float4*)(Bbase + (size_t)k0 * H_);
        __syncthreads();
        As[lk + 0][lr] = av.x; As[lk + 1][lr] = av.y;
        As[lk + 2][lr] = av.z; As[lk + 3][lr] = av.w;
        *(float4*)&Bs[lkk][lm] = bv;
        __syncthreads();
        COMPUTE_TILE()
    }
    const float4 bb = *(const float4*)(b1 + (size_t)e * H_ + n0 + (tx << 2));
#pragma unroll
    for (int i = 0; i < 4; ++i) {
        const int sp = (ty << 2) + i;
        float* crow = h + ((size_t)e * (B_ * SP_) + b * SP_ + sp) * H_ + n0 + (tx << 2);
        float4 o;
        float v;
        v = acc[i][0] + bb.x; o.x = 0.5f * v * (1.0f + erff(v * 0.70710678118654752f));
        v = acc[i][1] + bb.y; o.y = 0.5f * v * (1.0f + erff(v * 0.70710678118654752f));
        v = acc[i][2] + bb.z; o.z = 0.5f * v * (1.0f + erff(v * 0.70710678118654752f));
        v = acc[i][3] + bb.w; o.w = 0.5f * v * (1.0f + erff(v * 0.70710678118654752f));
        *(float4*)crow = o;
    }
}

// ---------------- kernel 6: slot_out = h @ W2[e] + b2[e] ----------------
__global__ __launch_bounds__(256) void k_ffn2(const float* __restrict__ h,
                                              const float* __restrict__ W2,
                                              const float* __restrict__ b2,
                                              float* __restrict__ slot_out) {
    __shared__ float As[16][64];
    __shared__ float Bs[16][64];
    const int tid = threadIdx.x;
    const int tx = tid & 15, ty = tid >> 4;
    const int lr = tid >> 2, lk = (tid & 3) << 2;
    const int lkk = tid >> 4, lm = (tid & 15) << 2;
    const int n0 = blockIdx.x * 64;
    const int b  = blockIdx.y;
    const int e  = blockIdx.z;
    const float* Arow  = h + ((size_t)e * (B_ * SP_) + b * SP_ + lr) * H_ + lk;
    const float* Bbase = W2 + (size_t)e * H_ * D_ + (size_t)lkk * D_ + n0 + lm;
    float acc[4][4] = {};
    for (int k0 = 0; k0 < H_; k0 += 16) {
        float4 av = *(const float4*)(Arow + k0);
        float4 bv = *(const float4*)(Bbase + (size_t)k0 * D_);
        __syncthreads();
        As[lk + 0][lr] = av.x; As[lk + 1][lr] = av.y;
        As[lk + 2][lr] = av.z; As[lk + 3][lr] = av.w;
        *(float4*)&Bs[lkk][lm] = bv;
        __syncthreads();
        COMPUTE_TILE()
    }
    const float4 bb = *(const float4*)(b2 + (size_t)e * D_ + n0 + (tx << 2));
#pragma unroll
    for (int i = 0; i < 4; ++i) {
        const int sp = (ty << 2) + i;
        float4 o = make_float4(acc[i][0] + bb.x, acc[i][1] + bb.y,
                               acc[i][2] + bb.z, acc[i][3] + bb.w);
        *(float4*)(slot_out + ((size_t)(b * S_ + e * SP_ + sp)) * D_ + n0 + (tx << 2)) = o;
    }
}

// ---------------- kernel 7: out[b,t,:] = sum_s combine[b,t,s] * slot_out[b,s,:] ----------------
// A = logits (T x S) row-major with row-softmax transform; B = slot_out (S x D) k-major; K = S
__global__ __launch_bounds__(256) void k_out(const float* __restrict__ logits,
                                             const float* __restrict__ slot_out,
                                             const float* __restrict__ rowmax,
                                             const float* __restrict__ rowrcp,
                                             float* __restrict__ out) {
    __shared__ float As[16][64];
    __shared__ float Bs[16][64];
    const int tid = threadIdx.x;
    const int tx = tid & 15, ty = tid >> 4;
    const int lr = tid >> 2, lk = (tid & 3) << 2;
    const int lkk = tid >> 4, lm = (tid & 15) << 2;
    const int d0 = blockIdx.x * 64;
    const int t0 = blockIdx.y * 64;
    const int b  = blockIdx.z;
    const size_t nrow = (size_t)b * T_ + t0 + lr;
    const float rm = rowmax[nrow];
    const float rr = rowrcp[nrow];
    const float* Arow  = logits + nrow * S_ + lk;
    const float* Bbase = slot_out + ((size_t)b * S_ + lkk) * D_ + d0 + lm;
    float acc[4][4] = {};
    for (int k0 = 0; k0 < S_; k0 += 16) {
        float4 av = *(const float4*)(Arow + k0);
        float4 bv = *(const float4*)(Bbase + (size_t)k0 * D_);
        av.x = __expf(av.x - rm) * rr;
        av.y = __expf(av.y - rm) * rr;
        av.z = __expf(av.z - rm) * rr;
        av.w = __expf(av.w - rm) * rr;
        __syncthreads();
        As[lk + 0][lr] = av.x; As[lk + 1][lr] = av.y;
        As[lk + 2][lr] = av.z; As[lk + 3][lr] = av.w;
        *(float4*)&Bs[lkk][lm] = bv;
        __syncthreads();
        COMPUTE_TILE()
    }
#pragma unroll
    for (int i = 0; i < 4; ++i) {
        const int t = t0 + (ty << 2) + i;
        float4 o = make_float4(acc[i][0], acc[i][1], acc[i][2], acc[i][3]);
        *(float4*)(out + ((size_t)b * T_ + t) * D_ + d0 + (tx << 2)) = o;
    }
}

// ---------------- launch ----------------
extern "C" void kernel_launch(void* const* d_in, const int* in_sizes, int n_in,
                              void* d_out, int out_size, void* d_ws, size_t ws_size,
                              hipStream_t stream) {
    const float* x  = (const float*)d_in[0];
    const float* Wr = (const float*)d_in[1];
    const float* eb = (const float*)d_in[2];
    const float* W1 = (const float*)d_in[3];
    const float* b1 = (const float*)d_in[4];
    const float* W2 = (const float*)d_in[5];
    const float* b2 = (const float*)d_in[6];
    float* out = (float*)d_out;

    // workspace partition (floats)
    float* logits  = (float*)d_ws;                          // N*S          = 16,777,216
    float* pm      = logits  + (size_t)N_ * S_;             // 8*B*S        = 32,768
    float* pl      = pm      + (size_t)8 * B_ * S_;         // 32,768
    float* colmax  = pl      + (size_t)8 * B_ * S_;         // 4,096
    float* colrcp  = colmax  + (size_t)B_ * S_;             // 4,096
    float* rowmax  = colrcp  + (size_t)B_ * S_;             // 32,768
    float* rowrcp  = rowmax  + (size_t)N_;                  // 32,768
    float* slot_in = rowrcp  + (size_t)N_;                  // B*S*D        = 4,194,304
    float* hbuf    = slot_in + (size_t)B_ * S_ * D_;        // E*B*SP*H     = 8,388,608
    float* slot_out= hbuf    + (size_t)E_ * B_ * SP_ * H_;  // B*S*D        = 4,194,304

    k_logits  <<<dim3(S_ / 64, N_ / 64), 256, 0, stream>>>(x, Wr, eb, logits);
    k_colpart <<<dim3(S_ / 64, B_, 8),   256, 0, stream>>>(logits, pm, pl);
    k_colcomb <<<dim3((B_ * S_) / 256),  256, 0, stream>>>(pm, pl, colmax, colrcp);
    k_rowstats<<<dim3(N_ / 4),           256, 0, stream>>>(logits, rowmax, rowrcp);
    k_slotin  <<<dim3(D_ / 64, S_ / 64, B_), 256, 0, stream>>>(logits, x, colmax, colrcp, slot_in);
    k_ffn1    <<<dim3(H_ / 64, B_, E_),  256, 0, stream>>>(slot_in, W1, b1, hbuf);
    k_ffn2    <<<dim3(D_ / 64, B_, E_),  256, 0, stream>>>(hbuf, W2, b2, slot_out);
    k_out     <<<dim3(D_ / 64, T_ / 64, B_), 256, 0, stream>>>(logits, slot_out, rowmax, rowrcp, out);
}

// Round 6
// 857.660 us; speedup vs baseline: 2.6416x; 2.6416x over previous
//
#include <hip/hip_runtime.h>
#include <hip/hip_bf16.h>
#include <math.h>

#define B_  8
#define T_  4096
#define D_  1024
#define H_  2048
#define E_  8
#define SP_ 64
#define S_  512
#define N_  (B_ * T_)   // 32768

typedef __attribute__((ext_vector_type(8))) short short8v;
typedef __attribute__((ext_vector_type(4))) float f32x4;

__device__ __forceinline__ ushort f2bf(float f) {
    uint u = __float_as_uint(f);
    u += 0x7FFFu + ((u >> 16) & 1u);
    return (ushort)(u >> 16);
}

__device__ __forceinline__ void glds16(const void* g, void* l) {
    __builtin_amdgcn_global_load_lds(
        (const __attribute__((address_space(1))) void*)g,
        (__attribute__((address_space(3))) void*)l, 16, 0, 0);
}

// ================= MFMA GEMM core =================
// Block tile (MI*32) x (NI*32), BK=32, 4 waves in a 2x2 grid, wave tile (MI*16)x(NI*16).
// A: (M x K) row-major bf16 (k contiguous), pre-offset to (m0, 0), lda = K-stride.
// B: (N x K) row-major bf16 ("B^T"), pre-offset to (n0, 0).
// LDS layout per operand: slot = kg*ROWS + row (16B slots: 8 bf16 of k = kg*8..+7).
// Staged with global_load_lds (linear LDS dest = slot*16B, per-lane global src).
template<int MI, int NI>
__device__ __forceinline__ void gemm_core(
    const ushort* __restrict__ A, int lda,
    const ushort* __restrict__ B, int ldb,
    int K, ushort* lAs, ushort* lBs,
    f32x4 (&acc)[MI][NI])
{
    constexpr int AR = MI * 32;          // A tile rows
    constexpr int BR = NI * 32;          // B tile rows
    constexpr int ASLOTS = AR * 4;
    constexpr int BSLOTS = BR * 4;
    const int tid  = threadIdx.x;
    const int lane = tid & 63;
    const int wave = tid >> 6;
    const int wm = wave >> 1, wn = wave & 1;
    const int kg = lane >> 4, lr = lane & 15;
    const int aoff = (kg * AR + wm * (MI * 16) + lr) * 8;   // ushort idx
    const int boff = (kg * BR + wn * (NI * 16) + lr) * 8;

    for (int k0 = 0; k0 < K; k0 += 32) {
        __syncthreads();   // previous tile fully consumed
#pragma unroll
        for (int it = 0; it < ASLOTS / 256; ++it) {
            const int slot = it * 256 + tid;
            const int skg = slot / AR, srow = slot % AR;
            glds16(A + (size_t)srow * lda + k0 + skg * 8, lAs + slot * 8);
        }
#pragma unroll
        for (int it = 0; it < BSLOTS / 256; ++it) {
            const int slot = it * 256 + tid;
            const int skg = slot / BR, srow = slot % BR;
            glds16(B + (size_t)srow * ldb + k0 + skg * 8, lBs + slot * 8);
        }
        __syncthreads();   // compiler drains vmcnt before s_barrier
        short8v a[MI], b[NI];
#pragma unroll
        for (int i = 0; i < MI; ++i) a[i] = *(const short8v*)(lAs + aoff + i * 16 * 8);
#pragma unroll
        for (int i = 0; i < NI; ++i) b[i] = *(const short8v*)(lBs + boff + i * 16 * 8);
#pragma unroll
        for (int mi = 0; mi < MI; ++mi)
#pragma unroll
            for (int ni = 0; ni < NI; ++ni)
                acc[mi][ni] = __builtin_amdgcn_mfma_f32_16x16x32_bf16(
                    a[mi], b[ni], acc[mi][ni], 0, 0, 0);
    }
}

// ================= GEMM kernels =================

// G1: logits(N_,S_) = xb(N_,D_) @ Wrb(S_,D_)^T + eb[s>>6]
__global__ __launch_bounds__(256) void g_logits(const ushort* __restrict__ xb,
                                                const ushort* __restrict__ Wrb,
                                                const float* __restrict__ eb,
                                                float* __restrict__ logits) {
    __shared__ __align__(16) ushort lAs[4096];
    __shared__ __align__(16) ushort lBs[4096];
    const int n0 = blockIdx.x * 128;
    const int m0 = blockIdx.y * 128;
    f32x4 acc[4][4] = {};
    gemm_core<4,4>(xb + (size_t)m0 * D_, D_, Wrb + (size_t)n0 * D_, D_, D_, lAs, lBs, acc);
    const int lane = threadIdx.x & 63;
    const int wave = threadIdx.x >> 6;
    const int rb = (wave >> 1) * 64 + ((lane >> 4) << 2);
    const int cb = (wave & 1) * 64 + (lane & 15);
#pragma unroll
    for (int mi = 0; mi < 4; ++mi)
#pragma unroll
        for (int ni = 0; ni < 4; ++ni) {
            const int col = n0 + cb + ni * 16;
            const float bias = eb[col >> 6];
#pragma unroll
            for (int r = 0; r < 4; ++r) {
                const int row = m0 + rb + mi * 16 + r;
                logits[(size_t)row * S_ + col] = acc[mi][ni][r] + bias;
            }
        }
}

// G2: slot_in: per b, C(s,d) = dT(b,s,t) @ xt(b,d,t)^T ; out bf16 (E,B,SP,D)
__global__ __launch_bounds__(256) void g_slotin(const ushort* __restrict__ dT,
                                                const ushort* __restrict__ xt,
                                                ushort* __restrict__ sInb) {
    __shared__ __align__(16) ushort lAs[2048];
    __shared__ __align__(16) ushort lBs[4096];
    const int n0 = blockIdx.x * 128;   // d
    const int m0 = blockIdx.y * 64;    // s
    const int b  = blockIdx.z;
    f32x4 acc[2][4] = {};
    gemm_core<2,4>(dT + ((size_t)b * S_ + m0) * T_, T_,
                   xt + ((size_t)b * D_ + n0) * T_, T_, T_, lAs, lBs, acc);
    const int lane = threadIdx.x & 63;
    const int wave = threadIdx.x >> 6;
    const int rb = (wave >> 1) * 32 + ((lane >> 4) << 2);
    const int cb = (wave & 1) * 64 + (lane & 15);
#pragma unroll
    for (int mi = 0; mi < 2; ++mi)
#pragma unroll
        for (int ni = 0; ni < 4; ++ni) {
            const int d = n0 + cb + ni * 16;
#pragma unroll
            for (int r = 0; r < 4; ++r) {
                const int s = m0 + rb + mi * 16 + r;
                const int e = s >> 6, sp = s & 63;
                sInb[(((size_t)e * B_ + b) * SP_ + sp) * D_ + d] = f2bf(acc[mi][ni][r]);
            }
        }
}

// G3: per e, h(row,hc) = gelu(sInb(e,row,:) @ W1t(e,hc,:)^T + b1[e,hc]); rows = b*64+sp
__global__ __launch_bounds__(256) void g_ffn1(const ushort* __restrict__ sInb,
                                              const ushort* __restrict__ W1t,
                                              const float* __restrict__ b1,
                                              ushort* __restrict__ hb) {
    __shared__ __align__(16) ushort lAs[2048];
    __shared__ __align__(16) ushort lBs[4096];
    const int n0 = blockIdx.x * 128;   // h col
    const int m0 = blockIdx.y * 64;    // row
    const int e  = blockIdx.z;
    f32x4 acc[2][4] = {};
    gemm_core<2,4>(sInb + ((size_t)e * (B_ * SP_) + m0) * D_, D_,
                   W1t + ((size_t)e * H_ + n0) * D_, D_, D_, lAs, lBs, acc);
    const int lane = threadIdx.x & 63;
    const int wave = threadIdx.x >> 6;
    const int rb = (wave >> 1) * 32 + ((lane >> 4) << 2);
    const int cb = (wave & 1) * 64 + (lane & 15);
#pragma unroll
    for (int mi = 0; mi < 2; ++mi)
#pragma unroll
        for (int ni = 0; ni < 4; ++ni) {
            const int hc = n0 + cb + ni * 16;
            const float bias = b1[(size_t)e * H_ + hc];
#pragma unroll
            for (int r = 0; r < 4; ++r) {
                const int row = m0 + rb + mi * 16 + r;
                float v = acc[mi][ni][r] + bias;
                v = 0.5f * v * (1.0f + erff(v * 0.70710678f));
                hb[((size_t)e * (B_ * SP_) + row) * H_ + hc] = f2bf(v);
            }
        }
}

// G4: per e, slot_out = hb(e) @ W2t(e)^T + b2[e]; out bf16 (B,S,D)
__global__ __launch_bounds__(256) void g_ffn2(const ushort* __restrict__ hb,
                                              const ushort* __restrict__ W2t,
                                              const float* __restrict__ b2,
                                              ushort* __restrict__ sOut) {
    __shared__ __align__(16) ushort lAs[2048];
    __shared__ __align__(16) ushort lBs[4096];
    const int n0 = blockIdx.x * 128;   // d
    const int m0 = blockIdx.y * 64;    // row
    const int e  = blockIdx.z;
    f32x4 acc[2][4] = {};
    gemm_core<2,4>(hb + ((size_t)e * (B_ * SP_) + m0) * H_, H_,
                   W2t + ((size_t)e * D_ + n0) * H_, H_, H_, lAs, lBs, acc);
    const int lane = threadIdx.x & 63;
    const int wave = threadIdx.x >> 6;
    const int rb = (wave >> 1) * 32 + ((lane >> 4) << 2);
    const int cb = (wave & 1) * 64 + (lane & 15);
#pragma unroll
    for (int mi = 0; mi < 2; ++mi)
#pragma unroll
        for (int ni = 0; ni < 4; ++ni) {
            const int d = n0 + cb + ni * 16;
            const float bias = b2[(size_t)e * D_ + d];
#pragma unroll
            for (int r = 0; r < 4; ++r) {
                const int row = m0 + rb + mi * 16 + r;
                const int bb = row >> 6, sp = row & 63;
                sOut[((size_t)bb * S_ + e * SP_ + sp) * D_ + d] = f2bf(acc[mi][ni][r] + bias);
            }
        }
}

// G5: per b, out(t,d) = cB(b,t,s) @ soT(b,d,s)^T  (fp32 out)
__global__ __launch_bounds__(256) void g_out(const ushort* __restrict__ cB,
                                             const ushort* __restrict__ soT,
                                             float* __restrict__ out) {
    __shared__ __align__(16) ushort lAs[4096];
    __shared__ __align__(16) ushort lBs[4096];
    const int n0 = blockIdx.x * 128;   // d
    const int m0 = blockIdx.y * 128;   // t
    const int b  = blockIdx.z;
    f32x4 acc[4][4] = {};
    gemm_core<4,4>(cB + ((size_t)b * T_ + m0) * S_, S_,
                   soT + ((size_t)b * D_ + n0) * S_, S_, S_, lAs, lBs, acc);
    const int lane = threadIdx.x & 63;
    const int wave = threadIdx.x >> 6;
    const int rb = (wave >> 1) * 64 + ((lane >> 4) << 2);
    const int cb2 = (wave & 1) * 64 + (lane & 15);
#pragma unroll
    for (int mi = 0; mi < 4; ++mi)
#pragma unroll
        for (int ni = 0; ni < 4; ++ni) {
            const int d = n0 + cb2 + ni * 16;
#pragma unroll
            for (int r = 0; r < 4; ++r) {
                const int t = m0 + rb + mi * 16 + r;
                out[((size_t)b * T_ + t) * D_ + d] = acc[mi][ni][r];
            }
        }
}

// ================= auxiliary kernels =================

// flat fp32 -> bf16
__global__ __launch_bounds__(256) void k_cvt(const float* __restrict__ in,
                                             ushort* __restrict__ out, int n4) {
    const int i = blockIdx.x * 256 + threadIdx.x;
    if (i < n4) {
        float4 v = ((const float4*)in)[i];
        ushort4 o;
        o.x = f2bf(v.x); o.y = f2bf(v.y); o.z = f2bf(v.z); o.w = f2bf(v.w);
        ((ushort4*)out)[i] = o;
    }
}

// tiled transpose fp32 (Z,R,C) -> bf16 (Z,C,R)
__global__ __launch_bounds__(256) void k_tr32(const float* __restrict__ in,
                                              ushort* __restrict__ out, int R, int C) {
    __shared__ float t[64][65];
    const int c0 = blockIdx.x * 64, r0 = blockIdx.y * 64;
    const size_t z = (size_t)blockIdx.z * R * C;
    const int lr = threadIdx.x >> 4;
    const int lc = (threadIdx.x & 15) * 4;
#pragma unroll
    for (int i = 0; i < 4; ++i) {
        float4 v = *(const float4*)(in + z + (size_t)(r0 + lr + i * 16) * C + c0 + lc);
        t[lr + i * 16][lc + 0] = v.x; t[lr + i * 16][lc + 1] = v.y;
        t[lr + i * 16][lc + 2] = v.z; t[lr + i * 16][lc + 3] = v.w;
    }
    __syncthreads();
#pragma unroll
    for (int i = 0; i < 4; ++i) {
        const int oc = lr + i * 16;
        ushort4 o;
        o.x = f2bf(t[lc + 0][oc]); o.y = f2bf(t[lc + 1][oc]);
        o.z = f2bf(t[lc + 2][oc]); o.w = f2bf(t[lc + 3][oc]);
        *(ushort4*)(out + z + (size_t)(c0 + oc) * R + r0 + lc) = o;
    }
}

// logits (B,T,S) fp32 -> dispatch^T bf16 (B,S,T), column softmax applied
__global__ __launch_bounds__(256) void k_dispT(const float* __restrict__ logits,
                                               const float* __restrict__ colmax,
                                               const float* __restrict__ colrcp,
                                               ushort* __restrict__ dT) {
    __shared__ float t[64][65];
    const int s0 = blockIdx.x * 64, t0 = blockIdx.y * 64, b = blockIdx.z;
    const int lr = threadIdx.x >> 4;
    const int lc = (threadIdx.x & 15) * 4;
#pragma unroll
    for (int i = 0; i < 4; ++i) {
        float4 v = *(const float4*)(logits + ((size_t)b * T_ + t0 + lr + i * 16) * S_ + s0 + lc);
        t[lr + i * 16][lc + 0] = v.x; t[lr + i * 16][lc + 1] = v.y;
        t[lr + i * 16][lc + 2] = v.z; t[lr + i * 16][lc + 3] = v.w;
    }
    __syncthreads();
#pragma unroll
    for (int i = 0; i < 4; ++i) {
        const int os = lr + i * 16;
        const float cm = colmax[b * S_ + s0 + os];
        const float cr = colrcp[b * S_ + s0 + os];
        ushort4 o;
        o.x = f2bf(__expf(t[lc + 0][os] - cm) * cr);
        o.y = f2bf(__expf(t[lc + 1][os] - cm) * cr);
        o.z = f2bf(__expf(t[lc + 2][os] - cm) * cr);
        o.w = f2bf(__expf(t[lc + 3][os] - cm) * cr);
        *(ushort4*)(dT + ((size_t)b * S_ + s0 + os) * T_ + t0 + lc) = o;
    }
}

// logits (B,T,S) fp32 -> combine bf16 (B,T,S), row softmax applied
__global__ __launch_bounds__(256) void k_combB(const float* __restrict__ logits,
                                               const float* __restrict__ rowmax,
                                               const float* __restrict__ rowrcp,
                                               ushort* __restrict__ cB) {
    const size_t i = (size_t)blockIdx.x * 256 + threadIdx.x;  // over N_*S_/4
    float4 v = ((const float4*)logits)[i];
    const size_t n = i >> 7;   // S_/4 = 128 float4 per row
    const float rm = rowmax[n], rr = rowrcp[n];
    ushort4 o;
    o.x = f2bf(__expf(v.x - rm) * rr);
    o.y = f2bf(__expf(v.y - rm) * rr);
    o.z = f2bf(__expf(v.z - rm) * rr);
    o.w = f2bf(__expf(v.w - rm) * rr);
    ((ushort4*)cB)[i] = o;
}

// bf16 transpose slot_out (B,S,D) -> soT (B,D,S)
__global__ __launch_bounds__(256) void k_tr16(const ushort* __restrict__ in,
                                              ushort* __restrict__ out) {
    __shared__ ushort t[64][68];
    const int d0 = blockIdx.x * 64, s0 = blockIdx.y * 64, b = blockIdx.z;
    const int lr = threadIdx.x >> 4;
    const int lc = (threadIdx.x & 15) * 4;
#pragma unroll
    for (int i = 0; i < 4; ++i) {
        ushort4 v = *(const ushort4*)(in + ((size_t)b * S_ + s0 + lr + i * 16) * D_ + d0 + lc);
        t[lr + i * 16][lc + 0] = v.x; t[lr + i * 16][lc + 1] = v.y;
        t[lr + i * 16][lc + 2] = v.z; t[lr + i * 16][lc + 3] = v.w;
    }
    __syncthreads();
#pragma unroll
    for (int i = 0; i < 4; ++i) {
        const int od = lr + i * 16;
        ushort4 o;
        o.x = t[lc + 0][od]; o.y = t[lc + 1][od];
        o.z = t[lc + 2][od]; o.w = t[lc + 3][od];
        *(ushort4*)(out + ((size_t)b * D_ + d0 + od) * S_ + s0 + lc) = o;
    }
}

// ---- softmax stats (fp32 logits) ----
__global__ __launch_bounds__(256) void k_colpart(const float* __restrict__ logits,
                                                 float* __restrict__ pm,
                                                 float* __restrict__ pl) {
    const int tid = threadIdx.x;
    const int sl = tid & 63;
    const int s = blockIdx.x * 64 + sl;
    const int b = blockIdx.y;
    const int c = blockIdx.z;
    const int tg = tid >> 6;
    const int t0 = c * (T_ / 8);
    float m = -1e30f, l = 0.f;
    for (int t = t0 + tg; t < t0 + T_ / 8; t += 4) {
        float v = logits[((size_t)b * T_ + t) * S_ + s];
        if (v > m) { l = l * __expf(m - v) + 1.0f; m = v; }
        else       { l += __expf(v - m); }
    }
    __shared__ float sm[4][64], sl2[4][64];
    sm[tg][sl] = m; sl2[tg][sl] = l;
    __syncthreads();
    if (tg == 0) {
#pragma unroll
        for (int g = 1; g < 4; ++g) {
            float m2 = sm[g][sl], l2 = sl2[g][sl];
            float mn = fmaxf(m, m2);
            l = l * __expf(m - mn) + l2 * __expf(m2 - mn);
            m = mn;
        }
        pm[(size_t)c * (B_ * S_) + b * S_ + s] = m;
        pl[(size_t)c * (B_ * S_) + b * S_ + s] = l;
    }
}

__global__ __launch_bounds__(256) void k_colcomb(const float* __restrict__ pm,
                                                 const float* __restrict__ pl,
                                                 float* __restrict__ colmax,
                                                 float* __restrict__ colrcp) {
    const int i = blockIdx.x * 256 + threadIdx.x;
    float m = -1e30f, l = 0.f;
#pragma unroll
    for (int c = 0; c < 8; ++c) {
        float m2 = pm[(size_t)c * (B_ * S_) + i];
        float l2 = pl[(size_t)c * (B_ * S_) + i];
        float mn = fmaxf(m, m2);
        l = l * __expf(m - mn) + l2 * __expf(m2 - mn);
        m = mn;
    }
    colmax[i] = m;
    colrcp[i] = 1.0f / l;
}

__global__ __launch_bounds__(256) void k_rowstats(const float* __restrict__ logits,
                                                  float* __restrict__ rowmax,
                                                  float* __restrict__ rowrcp) {
    const int tid = threadIdx.x;
    const int lane = tid & 63;
    const int n = blockIdx.x * 4 + (tid >> 6);
    const float* row = logits + (size_t)n * S_;
    float v[8];
    float m = -1e30f;
#pragma unroll
    for (int i = 0; i < 8; ++i) { v[i] = row[lane + i * 64]; m = fmaxf(m, v[i]); }
#pragma unroll
    for (int off = 32; off; off >>= 1) m = fmaxf(m, __shfl_xor(m, off, 64));
    float l = 0.f;
#pragma unroll
    for (int i = 0; i < 8; ++i) l += __expf(v[i] - m);
#pragma unroll
    for (int off = 32; off; off >>= 1) l += __shfl_xor(l, off, 64);
    if (lane == 0) { rowmax[n] = m; rowrcp[n] = 1.0f / l; }
}

// ================= launch =================
extern "C" void kernel_launch(void* const* d_in, const int* in_sizes, int n_in,
                              void* d_out, int out_size, void* d_ws, size_t ws_size,
                              hipStream_t stream) {
    const float* x  = (const float*)d_in[0];
    const float* Wr = (const float*)d_in[1];
    const float* eb = (const float*)d_in[2];
    const float* W1 = (const float*)d_in[3];
    const float* b1 = (const float*)d_in[4];
    const float* W2 = (const float*)d_in[5];
    const float* b2 = (const float*)d_in[6];
    float* out = (float*)d_out;

    char* w = (char*)d_ws;
    float* logits = (float*)w;               w += (size_t)N_ * S_ * 4;        // 64 MB
    ushort* W1t = (ushort*)logits;                                            // alias (logits dead)
    ushort* W2t = W1t + (size_t)E_ * H_ * D_;
    ushort* xb = (ushort*)w;                 w += (size_t)N_ * D_ * 2;        // 64 MB
    ushort* xt = xb;                                                          // alias (xb dead after G1)
    ushort* Wrb = (ushort*)w;                w += (size_t)S_ * D_ * 2;        // 1 MB
    ushort* dT = (ushort*)w;                 w += (size_t)B_ * S_ * T_ * 2;   // 32 MB
    ushort* cB = dT;                                                          // alias (dT dead after G2)
    ushort* sInb = (ushort*)w;               w += (size_t)B_ * S_ * D_ * 2;   // 8 MB
    ushort* hb = (ushort*)w;                 w += (size_t)E_ * B_ * SP_ * H_ * 2; // 16 MB
    ushort* sOut = (ushort*)w;               w += (size_t)B_ * S_ * D_ * 2;   // 8 MB
    ushort* soT = (ushort*)w;                w += (size_t)B_ * S_ * D_ * 2;   // 8 MB
    float* pm = (float*)w;                   w += (size_t)8 * B_ * S_ * 4;
    float* pl = (float*)w;                   w += (size_t)8 * B_ * S_ * 4;
    float* colmax = (float*)w;               w += (size_t)B_ * S_ * 4;
    float* colrcp = (float*)w;               w += (size_t)B_ * S_ * 4;
    float* rowmax = (float*)w;               w += (size_t)N_ * 4;
    float* rowrcp = (float*)w;               w += (size_t)N_ * 4;

    k_cvt     <<<dim3((N_ * D_ / 4 + 255) / 256), 256, 0, stream>>>(x, xb, N_ * D_ / 4);
    k_cvt     <<<dim3((S_ * D_ / 4 + 255) / 256), 256, 0, stream>>>(Wr, Wrb, S_ * D_ / 4);
    g_logits  <<<dim3(S_ / 128, N_ / 128), 256, 0, stream>>>(xb, Wrb, eb, logits);
    k_colpart <<<dim3(S_ / 64, B_, 8), 256, 0, stream>>>(logits, pm, pl);
    k_colcomb <<<dim3(B_ * S_ / 256), 256, 0, stream>>>(pm, pl, colmax, colrcp);
    k_rowstats<<<dim3(N_ / 4), 256, 0, stream>>>(logits, rowmax, rowrcp);
    k_tr32    <<<dim3(D_ / 64, T_ / 64, B_), 256, 0, stream>>>(x, xt, T_, D_);       // xt
    k_dispT   <<<dim3(S_ / 64, T_ / 64, B_), 256, 0, stream>>>(logits, colmax, colrcp, dT);
    g_slotin  <<<dim3(D_ / 128, S_ / 64, B_), 256, 0, stream>>>(dT, xt, sInb);
    k_combB   <<<dim3(N_ * S_ / 4 / 256), 256, 0, stream>>>(logits, rowmax, rowrcp, cB);
    k_tr32    <<<dim3(H_ / 64, D_ / 64, E_), 256, 0, stream>>>(W1, W1t, D_, H_);
    k_tr32    <<<dim3(D_ / 64, H_ / 64, E_), 256, 0, stream>>>(W2, W2t, H_, D_);
    g_ffn1    <<<dim3(H_ / 128, (B_ * SP_) / 64, E_), 256, 0, stream>>>(sInb, W1t, b1, hb);
    g_ffn2    <<<dim3(D_ / 128, (B_ * SP_) / 64, E_), 256, 0, stream>>>(hb, W2t, b2, sOut);
    k_tr16    <<<dim3(D_ / 64, S_ / 64, B_), 256, 0, stream>>>(sOut, soT);
    g_out     <<<dim3(D_ / 128, T_ / 128, B_), 256, 0, stream>>>(cB, soT, out);
}